// Round 2
// baseline (161.804 us; speedup 1.0000x reference)
//
#include <hip/hip_runtime.h>

// TextureMartingaleModule: 3x3 zero-padded GLCM features on (8,16,256,256) f32.
// Out (8,64,256,256) f32, outc = c*4 + {contrast, energy, entropy, homogeneity}.
// M = exp(log(f+EPS) - 0.5) = (f+EPS)*exp(-0.5)  (theta=1), folded into one FMA.
//
// One wave = one 4-row x 256-col stripe of one plane. Lane handles 4 columns.
// v2 changes vs 158.7us baseline:
//  - Rolling 4-slot row buffer (48 regs) instead of win[6][6]+pl[6][6] (72 regs):
//    VGPR down, __launch_bounds__(256,4) pins 4 waves/SIMD.
//  - S = sum2 - sum*mean (separable, reuses energy's column sums) replaces the
//    9-FMA explicit deviation accumulation per pixel (-144 FMA/lane). fmaxf(,0)
//    guards cancellation; contrast is ~flat in S so 1e-6 abs error is harmless.
//  - v_rcp_f32 / v_sqrt_f32 (1 ulp) replace IEEE div/sqrt expansions
//    (2 divides + 1 sqrt per pixel were ~25 instrs; now 3).
//  - Nontemporal ext_vector float4 stores for the 134 MB write-only output.

#define GLCM_EPS 1e-6f
#define KSC 0.60653065971263342f           // exp(-0.5)
#define EKC (1e-6f * 0.60653065971263342f) // EPS * exp(-0.5)

typedef float vfloat4 __attribute__((ext_vector_type(4)));

template <int SA, int SB, int SC>
__device__ __forceinline__ void do_row(const float (&wa)[4][6],
                                       const float (&la)[4][6],
                                       float* __restrict__ out, size_t ob) {
  // Column sums over the 3 live input rows (6 columns incl. halo).
  float cs[6], cs2[6], cpl[6];
#pragma unroll
  for (int c = 0; c < 6; ++c) {
    float a = wa[SA][c], b = wa[SB][c], d = wa[SC][c];
    cs[c]  = a + b + d;
    cs2[c] = __fmaf_rn(a, a, __fmaf_rn(b, b, d * d));
    cpl[c] = la[SA][c] + la[SB][c] + la[SC][c];
  }

  vfloat4 M0, M1, M2, M3;
#pragma unroll
  for (int jj = 0; jj < 4; ++jj) {
    float sum  = cs[jj]  + cs[jj + 1]  + cs[jj + 2];
    float sum2 = cs2[jj] + cs2[jj + 1] + cs2[jj + 2];
    float spl  = cpl[jj] + cpl[jj + 1] + cpl[jj + 2];
    float mean = sum * (1.0f / 9.0f);

    // Sum of squared deviations, separable form. Guard tiny cancellation.
    float S = fmaxf(__fmaf_rn(-mean, sum, sum2), 0.0f);

    // Sum of |p - mean| (genuinely non-separable; v_sub + v_add-with-abs).
    float sab = 0.f;
#pragma unroll
    for (int c = 0; c < 3; ++c) {
      sab += fabsf(wa[SA][jj + c] - mean);
      sab += fabsf(wa[SB][jj + c] - mean);
      sab += fabsf(wa[SC][jj + c] - mean);
    }

    float stdv = __builtin_amdgcn_sqrtf(S * 0.125f) + GLCM_EPS;  // ddof=1
    float rt   = __builtin_amdgcn_rcpf(stdv * stdv);
    M0[jj] = __fmaf_rn(S * (KSC / 9.0f), rt, EKC);               // contrast
    M1[jj] = __fmaf_rn(sum2, (KSC / 9.0f), EKC);                 // energy
    M2[jj] = __fmaf_rn(spl, -(KSC / 9.0f), EKC);                 // entropy
    float hd = __fmaf_rn(sab, (1.0f / 9.0f), 1.0f);
    M3[jj] = __fmaf_rn(__builtin_amdgcn_rcpf(hd), KSC, EKC);     // homogeneity
  }

  __builtin_nontemporal_store(M0, reinterpret_cast<vfloat4*>(out + ob));
  __builtin_nontemporal_store(M1, reinterpret_cast<vfloat4*>(out + ob + 65536));
  __builtin_nontemporal_store(M2, reinterpret_cast<vfloat4*>(out + ob + 2 * 65536));
  __builtin_nontemporal_store(M3, reinterpret_cast<vfloat4*>(out + ob + 3 * 65536));
}

__global__ __launch_bounds__(256, 4) void glcm_martingale_kernel(
    const float* __restrict__ x, float* __restrict__ out) {
  const int W = 256, HW = 65536;

  const int lane   = threadIdx.x & 63;
  const int wv     = threadIdx.x >> 6;
  const int stripe = blockIdx.x * 4 + wv;   // 8192 stripes total
  const int bc     = stripe >> 6;           // plane (b*C + c); 64 stripes/plane
  const int h0     = (stripe & 63) << 2;    // first output row: 0..252
  const int w0     = lane << 2;             // first of this lane's 4 columns

  const float* __restrict__ plane = x + (size_t)bc * HW;

  // Rolling 4-slot buffer: slot = (input_row_index) & 3, rows h0-1 .. h0+4.
  float wa[4][6];  // raw values [left, x, y, z, w, right]
  float la[4][6];  // p * log(p + eps), computed once per element

#define LOAD_ROW(HH, S)                                                       \
  do {                                                                        \
    int hh_ = (HH);                                                           \
    float4 v = make_float4(0.f, 0.f, 0.f, 0.f);                               \
    if ((unsigned)hh_ < 256u)                                                 \
      v = *reinterpret_cast<const float4*>(plane + hh_ * W + w0);             \
    float L = __shfl_up(v.w, 1);                                              \
    float R = __shfl_down(v.x, 1);                                            \
    if (lane == 0)  L = 0.f;  /* zero pad at w = -1  */                       \
    if (lane == 63) R = 0.f;  /* zero pad at w = 256 */                       \
    wa[S][0] = L;   wa[S][1] = v.x; wa[S][2] = v.y;                           \
    wa[S][3] = v.z; wa[S][4] = v.w; wa[S][5] = R;                             \
    la[S][0] = L * __logf(L + GLCM_EPS);                                      \
    la[S][1] = v.x * __logf(v.x + GLCM_EPS);                                  \
    la[S][2] = v.y * __logf(v.y + GLCM_EPS);                                  \
    la[S][3] = v.z * __logf(v.z + GLCM_EPS);                                  \
    la[S][4] = v.w * __logf(v.w + GLCM_EPS);                                  \
    la[S][5] = R * __logf(R + GLCM_EPS);                                      \
  } while (0)

  LOAD_ROW(h0 - 1, 0);
  LOAD_ROW(h0,     1);
  LOAD_ROW(h0 + 1, 2);

  const size_t obase0 = (size_t)bc * 4 * HW + (size_t)h0 * W + w0;

  // Prefetch the next input row before computing each output row: the load is
  // issued early and its dependent log-VALU schedules under the compute.
  LOAD_ROW(h0 + 2, 3);
  do_row<0, 1, 2>(wa, la, out, obase0);
  LOAD_ROW(h0 + 3, 0);
  do_row<1, 2, 3>(wa, la, out, obase0 + W);
  LOAD_ROW(h0 + 4, 1);
  do_row<2, 3, 0>(wa, la, out, obase0 + 2 * W);
  do_row<3, 0, 1>(wa, la, out, obase0 + 3 * W);

#undef LOAD_ROW
}

extern "C" void kernel_launch(void* const* d_in, const int* in_sizes, int n_in,
                              void* d_out, int out_size, void* d_ws, size_t ws_size,
                              hipStream_t stream) {
  const float* x = (const float*)d_in[0];
  float* out = (float*)d_out;
  // 128 planes * 64 stripes = 8192 waves; 4 waves per 256-thread block.
  dim3 grid(8192 / 4), block(256);
  glcm_martingale_kernel<<<grid, block, 0, stream>>>(x, out);
}